// Round 1
// baseline (270.343 us; speedup 1.0000x reference)
//
#include <hip/hip_runtime.h>
#include <cstdint>
#include <cstddef>

#define SEQ 2048
#define DH 64
#define PDH 32

typedef __attribute__((ext_vector_type(8))) short bf16x8;
typedef __attribute__((ext_vector_type(4))) float f32x4;
typedef __attribute__((ext_vector_type(4))) short short4v;

__device__ __forceinline__ short f2bf(float f) {
    union { float f; unsigned u; } a; a.f = f;
    unsigned r = a.u + 0x7fffu + ((a.u >> 16) & 1u);
    return (short)(r >> 16);
}
__device__ __forceinline__ float clip5(float v) {
    return fminf(fmaxf(v, -5.0f), 5.0f);
}

// Block: 512 threads = 8 waves. Each block: one (bh, 256-q-row) strip.
// Wave w: 32 q-rows. Two passes: (0) row sums of exp(s-20), (1) write probs.
__global__ __launch_bounds__(512, 2)
void attn_map_kernel(const float* __restrict__ Kp, const float* __restrict__ Qp,
                     const float* __restrict__ PKp, const float* __restrict__ PQp,
                     const int* __restrict__ maskp, float* __restrict__ out)
{
    // K-tile staged in MFMA B-fragment order: [st(8)][frag(3)][lane(64)][8 bf16]
    __shared__ short lds_k[8 * 3 * 64 * 8];   // 24 KiB
    __shared__ float lds_madd[128];

    // XCD-aware block mapping: p%8 selects XCD; keep each bh's 8 q-blocks on one XCD.
    const int p = blockIdx.x;
    const int x = p & 7;
    const int slot = p >> 3;              // 0..31
    const int bh = ((slot >> 3) << 3) + x; // {x, x+8, x+16, x+24}
    const int qb = slot & 7;

    const int tid = threadIdx.x;
    const int lane = tid & 63;
    const int w = tid >> 6;
    const int l15 = lane & 15;
    const int l4 = lane >> 4;

    const int qw = qb * 256 + w * 32;

    const float* Qb  = Qp  + (size_t)bh * (SEQ * DH);
    const float* Kb  = Kp  + (size_t)bh * (SEQ * DH);
    const float* PQb = PQp + (size_t)bh * (SEQ * PDH);
    const float* PKb = PKp + (size_t)bh * (SEQ * PDH);
    const int*   mb  = maskp + (size_t)(bh >> 4) * SEQ;
    float* outb = out + (size_t)bh * SEQ * SEQ;

    // ---- Q / PQ fragments in registers (A operand), scales pre-applied ----
    // A layout (16x16x32): lane holds A[l&15][(l>>4)*8 + j]
    bf16x8 qa[2][3];
    #pragma unroll
    for (int g = 0; g < 2; ++g) {
        int row = qw + g * 16 + l15;
        #pragma unroll
        for (int f = 0; f < 2; ++f) {
            const float* src = Qb + (size_t)row * DH + f * 32 + l4 * 8;
            bf16x8 v;
            #pragma unroll
            for (int j = 0; j < 8; ++j) v[j] = f2bf(clip5(src[j]) * 0.125f);
            qa[g][f] = v;
        }
        {
            const float* src = PQb + (size_t)row * PDH + l4 * 8;
            bf16x8 v;
            #pragma unroll
            for (int j = 0; j < 8; ++j) v[j] = f2bf(clip5(src[j]) * 0.17677669529663687f);
            qa[g][2] = v;
        }
    }

    float ssum[2][4] = {{0.f,0.f,0.f,0.f},{0.f,0.f,0.f,0.f}};
    float inv[2][4];

    for (int pass = 0; pass < 2; ++pass) {
        for (int tile = 0; tile < 16; ++tile) {
            const int tile0 = tile * 128;

            // ---- stage 128 cols of K/PK into LDS as bf16 fragments ----
            if (tid < 128) {
                lds_madd[tid] = mb[tile0 + tid] ? -1e30f : 0.0f;
            }
            #pragma unroll
            for (int i = 0; i < 6; ++i) {
                int e = i * 512 + tid;        // 0..3071 float4s
                int col = e / 24;             // 24 float4 per col (96 d)
                int dq = e - col * 24;
                int d0 = dq * 4;
                int colg = tile0 + col;
                float4 v;
                int f, dd;
                if (d0 < 64) {
                    v = *reinterpret_cast<const float4*>(Kb + (size_t)colg * DH + d0);
                    f = d0 >> 5; dd = d0 & 31;
                } else {
                    v = *reinterpret_cast<const float4*>(PKb + (size_t)colg * PDH + (d0 - 64));
                    f = 2; dd = d0 - 64;
                }
                int ll = (col & 15) | ((dd >> 3) << 4);
                int st = col >> 4;
                int j = dd & 7;               // 0 or 4
                short4v s4;
                s4[0] = f2bf(clip5(v.x));
                s4[1] = f2bf(clip5(v.y));
                s4[2] = f2bf(clip5(v.z));
                s4[3] = f2bf(clip5(v.w));
                *reinterpret_cast<short4v*>(&lds_k[(((st * 3 + f) * 64 + ll) << 3) + j]) = s4;
            }
            __syncthreads();

            // ---- compute 256q x 128k scores, consume ----
            #pragma unroll
            for (int st = 0; st < 8; ++st) {
                const bf16x8 kb0 = *reinterpret_cast<const bf16x8*>(&lds_k[((st*3+0)*64 + lane) << 3]);
                const bf16x8 kb1 = *reinterpret_cast<const bf16x8*>(&lds_k[((st*3+1)*64 + lane) << 3]);
                const bf16x8 kb2 = *reinterpret_cast<const bf16x8*>(&lds_k[((st*3+2)*64 + lane) << 3]);
                const float madd = lds_madd[st * 16 + l15];
                #pragma unroll
                for (int g = 0; g < 2; ++g) {
                    f32x4 acc = {0.f, 0.f, 0.f, 0.f};
                    acc = __builtin_amdgcn_mfma_f32_16x16x32_bf16(qa[g][0], kb0, acc, 0, 0, 0);
                    acc = __builtin_amdgcn_mfma_f32_16x16x32_bf16(qa[g][1], kb1, acc, 0, 0, 0);
                    acc = __builtin_amdgcn_mfma_f32_16x16x32_bf16(qa[g][2], kb2, acc, 0, 0, 0);
                    if (pass == 0) {
                        #pragma unroll
                        for (int r = 0; r < 4; ++r)
                            ssum[g][r] += __expf(acc[r] - 20.0f + madd);
                    } else {
                        #pragma unroll
                        for (int r = 0; r < 4; ++r) {
                            float pv = __expf(acc[r] - 20.0f + madd) * inv[g][r];
                            int row = qw + g * 16 + l4 * 4 + r;
                            outb[(size_t)row * SEQ + (tile0 + st * 16 + l15)] = pv;
                        }
                    }
                }
            }
            __syncthreads();
        }
        if (pass == 0) {
            // reduce partial sums across the 16 lanes sharing each row
            #pragma unroll
            for (int g = 0; g < 2; ++g) {
                #pragma unroll
                for (int r = 0; r < 4; ++r) {
                    float s = ssum[g][r];
                    s += __shfl_xor(s, 1);
                    s += __shfl_xor(s, 2);
                    s += __shfl_xor(s, 4);
                    s += __shfl_xor(s, 8);
                    inv[g][r] = 1.0f / s;
                }
            }
        }
    }
}

extern "C" void kernel_launch(void* const* d_in, const int* in_sizes, int n_in,
                              void* d_out, int out_size, void* d_ws, size_t ws_size,
                              hipStream_t stream) {
    const float* keys      = (const float*)d_in[0];
    const float* queries   = (const float*)d_in[1];
    const float* pos_key   = (const float*)d_in[2];
    const float* pos_query = (const float*)d_in[3];
    const int*   mask      = (const int*)d_in[4];
    float* outp = (float*)d_out;
    attn_map_kernel<<<dim3(256), dim3(512), 0, stream>>>(keys, queries, pos_key, pos_query, mask, outp);
}

// Round 2
// 249.908 us; speedup vs baseline: 1.0818x; 1.0818x over previous
//
#include <hip/hip_runtime.h>
#include <cstdint>
#include <cstddef>

#define SEQ 2048
#define DH 64
#define PDH 32

typedef __attribute__((ext_vector_type(8))) short bf16x8;
typedef __attribute__((ext_vector_type(4))) float f32x4;
typedef __attribute__((ext_vector_type(4))) short short4v;

__device__ __forceinline__ short f2bf(float f) {
    union { float f; unsigned u; } a; a.f = f;
    unsigned r = a.u + 0x7fffu + ((a.u >> 16) & 1u);
    return (short)(r >> 16);
}
__device__ __forceinline__ float clip5(float v) {
    return fminf(fmaxf(v, -5.0f), 5.0f);
}

// 512 blocks x 512 threads (8 waves). Block: one (bh, 128-q-row) strip; wave: 16 rows.
// Pass 0: row sums of exp2(s') ; pass 1: recompute + write probs as float4.
// Scores computed in log2 domain: scales pre-multiplied by log2(e).
__global__ __launch_bounds__(512, 4)
void attn_map_kernel(const float* __restrict__ Kp, const float* __restrict__ Qp,
                     const float* __restrict__ PKp, const float* __restrict__ PQp,
                     const int* __restrict__ maskp, float* __restrict__ out)
{
    // K-tile staged in MFMA fragment order: [st(8)][frag(3)][lane(64)][8 bf16]
    __shared__ short lds_k[8 * 3 * 64 * 8];   // 24 KiB
    __shared__ float lds_madd[128];

    // XCD-aware mapping: p%8 = XCD; 4 bh per XCD (K panels stay L2-resident).
    const int p = blockIdx.x;
    const int x = p & 7;
    const int slot = p >> 3;               // 0..63
    const int bh = ((slot >> 4) << 3) + x; // {x, x+8, x+16, x+24}
    const int qb = slot & 15;

    const int tid = threadIdx.x;
    const int lane = tid & 63;
    const int w = tid >> 6;
    const int l15 = lane & 15;
    const int l4 = lane >> 4;

    const int qrow = qb * 128 + w * 16 + l15;   // this lane's q row (B-operand index)

    const float* Qb  = Qp  + (size_t)bh * (SEQ * DH);
    const float* Kb  = Kp  + (size_t)bh * (SEQ * DH);
    const float* PQb = PQp + (size_t)bh * (SEQ * PDH);
    const float* PKb = PKp + (size_t)bh * (SEQ * PDH);
    const int*   mb  = maskp + (size_t)(bh >> 4) * SEQ;
    float* orow = out + (size_t)bh * SEQ * SEQ + (size_t)qrow * SEQ;

    const float QS  = 0.125f * 1.4426950408889634f;              // SCALE * log2(e)
    const float PQS = 0.17677669529663687f * 1.4426950408889634f; // REL_SCALE * log2(e)
    const float SHIFT = 28.853900817779268f;                      // 20 * log2(e)

    // ---- Q / PQ fragments (B operand): lane holds Q[qrow][l4*8 + j] ----
    bf16x8 qa[3];
    #pragma unroll
    for (int f = 0; f < 2; ++f) {
        const float* src = Qb + (size_t)qrow * DH + f * 32 + l4 * 8;
        bf16x8 v;
        #pragma unroll
        for (int j = 0; j < 8; ++j) v[j] = f2bf(clip5(src[j]) * QS);
        qa[f] = v;
    }
    {
        const float* src = PQb + (size_t)qrow * PDH + l4 * 8;
        bf16x8 v;
        #pragma unroll
        for (int j = 0; j < 8; ++j) v[j] = f2bf(clip5(src[j]) * PQS);
        qa[2] = v;
    }

    float ssum = 0.0f;
    float inv = 0.0f;

    for (int pass = 0; pass < 2; ++pass) {
        for (int tile = 0; tile < 16; ++tile) {
            const int tile0 = tile * 128;

            // ---- stage 128 cols of K/PK into LDS as bf16 A-fragments ----
            if (tid < 128) {
                lds_madd[tid] = mb[tile0 + tid] ? -1e30f : 0.0f;
            }
            #pragma unroll
            for (int i = 0; i < 6; ++i) {
                int e = i * 512 + tid;        // 0..3071 float4s
                int col = e / 24;             // 24 float4 per col (96 d)
                int dq = e - col * 24;
                int d0 = dq * 4;
                int colg = tile0 + col;
                float4 v;
                int f, dd;
                if (d0 < 64) {
                    v = *reinterpret_cast<const float4*>(Kb + (size_t)colg * DH + d0);
                    f = d0 >> 5; dd = d0 & 31;
                } else {
                    v = *reinterpret_cast<const float4*>(PKb + (size_t)colg * PDH + (d0 - 64));
                    f = 2; dd = d0 - 64;
                }
                int ll = (col & 15) | ((dd >> 3) << 4);
                int st = col >> 4;
                int j = dd & 7;               // 0 or 4
                short4v s4;
                s4[0] = f2bf(clip5(v.x));
                s4[1] = f2bf(clip5(v.y));
                s4[2] = f2bf(clip5(v.z));
                s4[3] = f2bf(clip5(v.w));
                *reinterpret_cast<short4v*>(&lds_k[(((st * 3 + f) * 64 + ll) << 3) + j]) = s4;
            }
            __syncthreads();

            // ---- compute 128q x 128k scores; lane owns 4 consecutive k-cols of one q row ----
            #pragma unroll
            for (int st = 0; st < 8; ++st) {
                const bf16x8 kb0 = *reinterpret_cast<const bf16x8*>(&lds_k[((st*3+0)*64 + lane) << 3]);
                const bf16x8 kb1 = *reinterpret_cast<const bf16x8*>(&lds_k[((st*3+1)*64 + lane) << 3]);
                const bf16x8 kb2 = *reinterpret_cast<const bf16x8*>(&lds_k[((st*3+2)*64 + lane) << 3]);
                const f32x4 madd4 = *reinterpret_cast<const f32x4*>(&lds_madd[st * 16 + l4 * 4]);
                f32x4 acc = {0.f, 0.f, 0.f, 0.f};
                // swapped operands: D[k][q] -> lane holds q row = l15-group col, k = l4*4+r
                acc = __builtin_amdgcn_mfma_f32_16x16x32_bf16(kb0, qa[0], acc, 0, 0, 0);
                acc = __builtin_amdgcn_mfma_f32_16x16x32_bf16(kb1, qa[1], acc, 0, 0, 0);
                acc = __builtin_amdgcn_mfma_f32_16x16x32_bf16(kb2, qa[2], acc, 0, 0, 0);
                if (pass == 0) {
                    #pragma unroll
                    for (int r = 0; r < 4; ++r)
                        ssum += exp2f(acc[r] - SHIFT + madd4[r]);
                } else {
                    f32x4 pv;
                    #pragma unroll
                    for (int r = 0; r < 4; ++r)
                        pv[r] = exp2f(acc[r] - SHIFT + madd4[r]) * inv;
                    *reinterpret_cast<f32x4*>(orow + tile0 + st * 16 + l4 * 4) = pv;
                }
            }
            __syncthreads();
        }
        if (pass == 0) {
            // lanes sharing a q row differ only in bits 4,5 of lane id
            float s = ssum;
            s += __shfl_xor(s, 16);
            s += __shfl_xor(s, 32);
            inv = 1.0f / s;
        }
    }
}

extern "C" void kernel_launch(void* const* d_in, const int* in_sizes, int n_in,
                              void* d_out, int out_size, void* d_ws, size_t ws_size,
                              hipStream_t stream) {
    const float* keys      = (const float*)d_in[0];
    const float* queries   = (const float*)d_in[1];
    const float* pos_key   = (const float*)d_in[2];
    const float* pos_query = (const float*)d_in[3];
    const int*   mask      = (const int*)d_in[4];
    float* outp = (float*)d_out;
    attn_map_kernel<<<dim3(512), dim3(512), 0, stream>>>(keys, queries, pos_key, pos_query, mask, outp);
}

// Round 3
// 195.965 us; speedup vs baseline: 1.3795x; 1.2753x over previous
//
#include <hip/hip_runtime.h>
#include <cstdint>
#include <cstddef>

#define SEQ 2048
#define TILES 16
#define FRAG_SHORTS (8 * 3 * 64 * 8)   // 12288 bf16 per 128-col tile

typedef __attribute__((ext_vector_type(8))) short bf16x8;
typedef __attribute__((ext_vector_type(4))) float f32x4;
typedef __attribute__((ext_vector_type(4))) short short4v;
typedef __attribute__((ext_vector_type(4))) int int4v;

__device__ __forceinline__ short f2bf(float f) {
    union { float f; unsigned u; } a; a.f = f;
    unsigned r = a.u + 0x7fffu + ((a.u >> 16) & 1u);
    return (short)(r >> 16);
}
__device__ __forceinline__ float clip5(float v) { return fminf(fmaxf(v, -5.0f), 5.0f); }
__device__ __forceinline__ float bflo2f(unsigned u) { union { unsigned u; float f; } a; a.u = u << 16; return a.f; }
__device__ __forceinline__ float bfhi2f(unsigned u) { union { unsigned u; float f; } a; a.u = u & 0xffff0000u; return a.f; }

// ---- prepass: K/PK f32 -> clipped bf16, MFMA A-fragment order ----
// ws layout: [bh(32)][tile(16)][st(8)][frag(3)][lane(64)][j(8)]
__global__ __launch_bounds__(256)
void prep_kernel(const float* __restrict__ Kp, const float* __restrict__ PKp,
                 short* __restrict__ wsK)
{
    int id = blockIdx.x * 256 + threadIdx.x;   // 786432 total lane-rows
    int lane = id & 63;
    int r = id >> 6;
    int frag = r % 3; r /= 3;
    int st = r & 7; r >>= 3;
    int tile = r & 15;
    int bh = r >> 4;
    int col = tile * 128 + st * 16 + (lane & 15);
    int hi8 = (lane >> 4) * 8;
    const float* src = (frag < 2)
        ? Kp  + ((size_t)(bh * SEQ + col)) * 64 + frag * 32 + hi8
        : PKp + ((size_t)(bh * SEQ + col)) * 32 + hi8;
    float4 a = reinterpret_cast<const float4*>(src)[0];
    float4 b = reinterpret_cast<const float4*>(src)[1];
    bf16x8 o;
    o[0] = f2bf(clip5(a.x)); o[1] = f2bf(clip5(a.y));
    o[2] = f2bf(clip5(a.z)); o[3] = f2bf(clip5(a.w));
    o[4] = f2bf(clip5(b.x)); o[5] = f2bf(clip5(b.y));
    o[6] = f2bf(clip5(b.z)); o[7] = f2bf(clip5(b.w));
    *reinterpret_cast<bf16x8*>(wsK + (size_t)id * 8) = o;
}

// one MFMA+exp+pack step for score sub-tile (t, st); results into pk[]
#define CSTEP(kb0, kb1, kb2, T, STI, ST) do {                                        \
    int4v mv = *reinterpret_cast<const int4v*>(mb + (T) * 128 + (ST) * 16 + l4 * 4); \
    f32x4 acc = {0.f, 0.f, 0.f, 0.f};                                                \
    acc = __builtin_amdgcn_mfma_f32_16x16x32_bf16(kb0, qa[0], acc, 0, 0, 0);         \
    acc = __builtin_amdgcn_mfma_f32_16x16x32_bf16(kb1, qa[1], acc, 0, 0, 0);         \
    acc = __builtin_amdgcn_mfma_f32_16x16x32_bf16(kb2, qa[2], acc, 0, 0, 0);         \
    float e0 = exp2f(acc[0] - SHIFT + (mv[0] ? -1e30f : 0.f));                       \
    float e1 = exp2f(acc[1] - SHIFT + (mv[1] ? -1e30f : 0.f));                       \
    float e2 = exp2f(acc[2] - SHIFT + (mv[2] ? -1e30f : 0.f));                       \
    float e3 = exp2f(acc[3] - SHIFT + (mv[3] ? -1e30f : 0.f));                       \
    ssum += (e0 + e1) + (e2 + e3);                                                   \
    unsigned u0, u1;                                                                 \
    asm("v_cvt_pk_bf16_f32 %0, %1, %2" : "=v"(u0) : "v"(e0), "v"(e1));               \
    asm("v_cvt_pk_bf16_f32 %0, %1, %2" : "=v"(u1) : "v"(e2), "v"(e3));               \
    pk[(T) * 4 + (STI) * 2]     = u0;                                                \
    pk[(T) * 4 + (STI) * 2 + 1] = u1;                                                \
} while (0)

// 2048 blocks x 512 thr (8 waves). Block: (bh, 32 q rows). Wave: rg=w&1 row half,
// cs=w>>1 col quarter; lane owns q-row l15, 4 consecutive k-cols per sub-tile.
// Single pass: P kept in registers as packed bf16 (64 VGPRs).
template<bool USEWS>
__global__ __launch_bounds__(512, 4)
void attn_map_kernel(const float* __restrict__ Kp, const float* __restrict__ Qp,
                     const float* __restrict__ PKp, const float* __restrict__ PQp,
                     const int* __restrict__ maskp, const short* __restrict__ wsK,
                     float* __restrict__ out)
{
    __shared__ float sred[8][16];

    // XCD-aware mapping: p%8 = XCD; 4 bh x 64 q-blocks per XCD.
    const int p = blockIdx.x;
    const int x = p & 7;
    const int slot = p >> 3;               // 0..255
    const int bh = x + 8 * (slot >> 6);    // {x, x+8, x+16, x+24}
    const int qb = slot & 63;              // 0..63

    const int tid = threadIdx.x;
    const int lane = tid & 63;
    const int w = tid >> 6;
    const int l15 = lane & 15;
    const int l4 = lane >> 4;
    const int rg = w & 1;
    const int cs = w >> 1;

    const int qrow = qb * 32 + rg * 16 + l15;

    const float* Qb  = Qp  + (size_t)bh * (SEQ * 64);
    const float* PQb = PQp + (size_t)bh * (SEQ * 32);
    const int*   mb  = maskp + (size_t)(bh >> 4) * SEQ;
    float* orow = out + (size_t)bh * SEQ * SEQ + (size_t)qrow * SEQ;

    const float QS  = 0.125f * 1.4426950408889634f;               // SCALE * log2(e)
    const float PQS = 0.17677669529663687f * 1.4426950408889634f; // REL_SCALE * log2(e)
    const float SHIFT = 28.853900817779268f;                      // 20 * log2(e)

    // Q / PQ fragments (B operand): lane holds Q[qrow][l4*8 + j], scales folded
    bf16x8 qa[3];
    #pragma unroll
    for (int f = 0; f < 2; ++f) {
        const float* src = Qb + (size_t)qrow * 64 + f * 32 + l4 * 8;
        bf16x8 v;
        #pragma unroll
        for (int j = 0; j < 8; ++j) v[j] = f2bf(clip5(src[j]) * QS);
        qa[f] = v;
    }
    {
        const float* src = PQb + (size_t)qrow * 32 + l4 * 8;
        bf16x8 v;
        #pragma unroll
        for (int j = 0; j < 8; ++j) v[j] = f2bf(clip5(src[j]) * PQS);
        qa[2] = v;
    }

    unsigned pk[64];   // packed bf16 P values: [tile(16)][sti(2)][pair(2)]
    float ssum = 0.0f;

    if constexpr (USEWS) {
        const short* kf = wsK + (size_t)bh * (TILES * FRAG_SHORTS);
        #pragma unroll
        for (int t = 0; t < TILES; ++t) {
            const short* kt = kf + t * FRAG_SHORTS;
            #pragma unroll
            for (int sti = 0; sti < 2; ++sti) {
                const int st = cs * 2 + sti;
                bf16x8 kb0 = *reinterpret_cast<const bf16x8*>(kt + ((st * 3 + 0) * 64 + lane) * 8);
                bf16x8 kb1 = *reinterpret_cast<const bf16x8*>(kt + ((st * 3 + 1) * 64 + lane) * 8);
                bf16x8 kb2 = *reinterpret_cast<const bf16x8*>(kt + ((st * 3 + 2) * 64 + lane) * 8);
                CSTEP(kb0, kb1, kb2, t, sti, st);
            }
        }
    } else {
        __shared__ short lds_k[FRAG_SHORTS];
        #pragma unroll
        for (int t = 0; t < TILES; ++t) {
            if (t > 0) __syncthreads();
            const int tile0 = t * 128;
            #pragma unroll
            for (int i = 0; i < 6; ++i) {
                int e = i * 512 + tid;
                int col = e / 24;
                int dq = e - col * 24;
                int d0 = dq * 4;
                int colg = tile0 + col;
                float4 v;
                int f, dd;
                if (d0 < 64) {
                    v = *reinterpret_cast<const float4*>(Kp + (size_t)bh * (SEQ * 64) + (size_t)colg * 64 + d0);
                    f = d0 >> 5; dd = d0 & 31;
                } else {
                    v = *reinterpret_cast<const float4*>(PKp + (size_t)bh * (SEQ * 32) + (size_t)colg * 32 + (d0 - 64));
                    f = 2; dd = d0 - 64;
                }
                int ll = (col & 15) | ((dd >> 3) << 4);
                int st2 = col >> 4;
                int j = dd & 7;
                short4v s4;
                s4[0] = f2bf(clip5(v.x)); s4[1] = f2bf(clip5(v.y));
                s4[2] = f2bf(clip5(v.z)); s4[3] = f2bf(clip5(v.w));
                *reinterpret_cast<short4v*>(&lds_k[(((st2 * 3 + f) * 64 + ll) << 3) + j]) = s4;
            }
            __syncthreads();
            #pragma unroll
            for (int sti = 0; sti < 2; ++sti) {
                const int st = cs * 2 + sti;
                bf16x8 kb0 = *reinterpret_cast<const bf16x8*>(&lds_k[((st * 3 + 0) * 64 + lane) << 3]);
                bf16x8 kb1 = *reinterpret_cast<const bf16x8*>(&lds_k[((st * 3 + 1) * 64 + lane) << 3]);
                bf16x8 kb2 = *reinterpret_cast<const bf16x8*>(&lds_k[((st * 3 + 2) * 64 + lane) << 3]);
                CSTEP(kb0, kb1, kb2, t, sti, st);
            }
        }
    }

    // ---- row-sum reduce: in-wave (lanes sharing l15) then cross-wave via LDS ----
    float s = ssum;
    s += __shfl_xor(s, 16);
    s += __shfl_xor(s, 32);
    if (lane < 16) sred[w][l15] = s;
    __syncthreads();
    const float rs = sred[rg][l15] + sred[2 + rg][l15] + sred[4 + rg][l15] + sred[6 + rg][l15];
    const float inv = 1.0f / rs;

    // ---- scale + store: float4 per lane, 128B/row/tile per wave ----
    #pragma unroll
    for (int t = 0; t < TILES; ++t) {
        #pragma unroll
        for (int sti = 0; sti < 2; ++sti) {
            unsigned u0 = pk[t * 4 + sti * 2];
            unsigned u1 = pk[t * 4 + sti * 2 + 1];
            f32x4 pv = { bflo2f(u0) * inv, bfhi2f(u0) * inv,
                         bflo2f(u1) * inv, bfhi2f(u1) * inv };
            *reinterpret_cast<f32x4*>(orow + t * 128 + (cs * 2 + sti) * 16 + l4 * 4) = pv;
        }
    }
}

extern "C" void kernel_launch(void* const* d_in, const int* in_sizes, int n_in,
                              void* d_out, int out_size, void* d_ws, size_t ws_size,
                              hipStream_t stream) {
    const float* keys      = (const float*)d_in[0];
    const float* queries   = (const float*)d_in[1];
    const float* pos_key   = (const float*)d_in[2];
    const float* pos_query = (const float*)d_in[3];
    const int*   mask      = (const int*)d_in[4];
    float* outp = (float*)d_out;

    const size_t need = (size_t)32 * TILES * FRAG_SHORTS * sizeof(short); // 12.58 MB
    if (ws_size >= need) {
        short* wsK = (short*)d_ws;
        prep_kernel<<<dim3(3072), dim3(256), 0, stream>>>(keys, pos_key, wsK);
        attn_map_kernel<true><<<dim3(2048), dim3(512), 0, stream>>>(
            keys, queries, pos_key, pos_query, mask, wsK, outp);
    } else {
        attn_map_kernel<false><<<dim3(2048), dim3(512), 0, stream>>>(
            keys, queries, pos_key, pos_query, mask, nullptr, outp);
    }
}

// Round 4
// 183.991 us; speedup vs baseline: 1.4693x; 1.0651x over previous
//
#include <hip/hip_runtime.h>
#include <cstdint>
#include <cstddef>

#define SEQ 2048
#define TILES 16
#define FRAG_SHORTS 12288                 // bf16 per 128-col tile (8 st * 3 frag * 64 lane * 8)
#define FRAG_BYTES  24576

typedef __attribute__((ext_vector_type(8))) short bf16x8;
typedef __attribute__((ext_vector_type(4))) float f32x4;
typedef __attribute__((ext_vector_type(4))) short short4v;

__device__ __forceinline__ short f2bf(float f) {
    union { float f; unsigned u; } a; a.f = f;
    unsigned r = a.u + 0x7fffu + ((a.u >> 16) & 1u);
    return (short)(r >> 16);
}
__device__ __forceinline__ float clip5(float v) { return fminf(fmaxf(v, -5.0f), 5.0f); }
__device__ __forceinline__ float bflo2f(unsigned u) { union { unsigned u; float f; } a; a.u = u << 16; return a.f; }
__device__ __forceinline__ float bfhi2f(unsigned u) { union { unsigned u; float f; } a; a.u = u & 0xffff0000u; return a.f; }

// ---- prepass: K/PK f32 -> clipped bf16 in MFMA A-fragment order (coalesced reads) ----
// ws layout: [bh(32)][tile(16)][st(8)][frag(3)][lane(64)][j(8)]
__global__ __launch_bounds__(256)
void prep_kernel(const float* __restrict__ Kp, const float* __restrict__ PKp,
                 short* __restrict__ wsK)
{
    int id = blockIdx.x * 256 + threadIdx.x;   // 65536 rows * 24 float4
    int q = id % 24;
    int row = id / 24;            // bh*2048 + col
    int bh = row >> 11;
    int col = row & 2047;
    int tile = col >> 7;
    int st = (col >> 4) & 7;
    int l15 = col & 15;
    float4 v;
    int f, dd;
    if (q < 16) {                 // keys: 16 float4 per row, contiguous
        v = reinterpret_cast<const float4*>(Kp)[(size_t)row * 16 + q];
        f = q >> 3;
        dd = (q & 7) * 4;
    } else {                      // pos_key: 8 float4 per row
        v = reinterpret_cast<const float4*>(PKp)[(size_t)row * 8 + (q - 16)];
        f = 2;
        dd = (q - 16) * 4;
    }
    int ll = l15 | ((dd >> 3) << 4);
    int j = dd & 7;
    short4v s4;
    s4[0] = f2bf(clip5(v.x)); s4[1] = f2bf(clip5(v.y));
    s4[2] = f2bf(clip5(v.z)); s4[3] = f2bf(clip5(v.w));
    *reinterpret_cast<short4v*>(wsK + ((size_t)bh * TILES + tile) * FRAG_SHORTS
                                + (((st * 3 + f) * 64 + ll) << 3) + j) = s4;
}

// one MFMA+exp+pack step for score sub-tile (t, st)
#define CSTEP(kb0, kb1, kb2, T, STI, ST) do {                                        \
    f32x4 madd4 = *reinterpret_cast<const f32x4*>(&lds_madd[(T) * 128 + (ST) * 16 + l4 * 4]); \
    f32x4 acc = {0.f, 0.f, 0.f, 0.f};                                                \
    acc = __builtin_amdgcn_mfma_f32_16x16x32_bf16(kb0, qa[0], acc, 0, 0, 0);         \
    acc = __builtin_amdgcn_mfma_f32_16x16x32_bf16(kb1, qa[1], acc, 0, 0, 0);         \
    acc = __builtin_amdgcn_mfma_f32_16x16x32_bf16(kb2, qa[2], acc, 0, 0, 0);         \
    float e0 = exp2f(acc[0] - SHIFT + madd4[0]);                                     \
    float e1 = exp2f(acc[1] - SHIFT + madd4[1]);                                     \
    float e2 = exp2f(acc[2] - SHIFT + madd4[2]);                                     \
    float e3 = exp2f(acc[3] - SHIFT + madd4[3]);                                     \
    ssum += (e0 + e1) + (e2 + e3);                                                   \
    unsigned u0, u1;                                                                 \
    asm("v_cvt_pk_bf16_f32 %0, %1, %2" : "=v"(u0) : "v"(e0), "v"(e1));               \
    asm("v_cvt_pk_bf16_f32 %0, %1, %2" : "=v"(u1) : "v"(e2), "v"(e3));               \
    pk[(T) * 4 + (STI) * 2]     = u0;                                                \
    pk[(T) * 4 + (STI) * 2 + 1] = u1;                                                \
} while (0)

// 2048 blocks x 512 thr (8 waves). Block: (bh, 32 q rows). Wave: rg=w&1 row half,
// cs=w>>1 col quarter; lane owns q-row l15, 4 consecutive k-cols per sub-tile.
// Single pass; K-frags double-buffered in LDS via async global_load_lds.
template<bool USEWS>
__global__ __launch_bounds__(512, 4)
void attn_map_kernel(const float* __restrict__ Kp, const float* __restrict__ Qp,
                     const float* __restrict__ PKp, const float* __restrict__ PQp,
                     const int* __restrict__ maskp, const short* __restrict__ wsK,
                     float* __restrict__ out)
{
    __shared__ short lds_k[2][FRAG_SHORTS];   // 48 KiB double buffer
    __shared__ float lds_madd[SEQ];           // 8 KiB mask-additive
    __shared__ float sred[8][16];

    // XCD-aware mapping: p%8 = XCD; 4 bh x 64 q-blocks per XCD.
    const int p = blockIdx.x;
    const int x = p & 7;
    const int slot = p >> 3;               // 0..255
    const int bh = x + 8 * (slot >> 6);    // {x, x+8, x+16, x+24}
    const int qb = slot & 63;              // 0..63

    const int tid = threadIdx.x;
    const int lane = tid & 63;
    const int w = tid >> 6;
    const int l15 = lane & 15;
    const int l4 = lane >> 4;
    const int rg = w & 1;
    const int cs = w >> 1;

    const int qrow = qb * 32 + rg * 16 + l15;

    const float* Qb  = Qp  + (size_t)bh * (SEQ * 64);
    const float* PQb = PQp + (size_t)bh * (SEQ * 32);
    const int*   mb  = maskp + (size_t)(bh >> 4) * SEQ;
    float* orow = out + (size_t)bh * SEQ * SEQ + (size_t)qrow * SEQ;

    const float QS  = 0.125f * 1.4426950408889634f;               // SCALE * log2(e)
    const float PQS = 0.17677669529663687f * 1.4426950408889634f; // REL_SCALE * log2(e)
    const float SHIFT = 28.853900817779268f;                      // 20 * log2(e)

    // ---- Q / PQ fragments (B operand): lane holds Q[qrow][l4*8 + j] ----
    bf16x8 qa[3];
    #pragma unroll
    for (int f = 0; f < 2; ++f) {
        const float* src = Qb + (size_t)qrow * 64 + f * 32 + l4 * 8;
        bf16x8 v;
        #pragma unroll
        for (int j = 0; j < 8; ++j) v[j] = f2bf(clip5(src[j]) * QS);
        qa[f] = v;
    }
    {
        const float* src = PQb + (size_t)qrow * 32 + l4 * 8;
        bf16x8 v;
        #pragma unroll
        for (int j = 0; j < 8; ++j) v[j] = f2bf(clip5(src[j]) * PQS);
        qa[2] = v;
    }

    // ---- mask -> LDS as additive floats ----
    #pragma unroll
    for (int i = 0; i < SEQ / 512; ++i) {
        int idx = i * 512 + tid;
        lds_madd[idx] = mb[idx] ? -1e30f : 0.0f;
    }

    const short* kf = USEWS ? (wsK + (size_t)bh * (TILES * FRAG_SHORTS)) : nullptr;

    unsigned pk[64];   // packed bf16 P: [tile(16)][sti(2)][pair(2)]
    float ssum = 0.0f;

    // ---- stage tile 0 ----
    if constexpr (USEWS) {
        #pragma unroll
        for (int c = 0; c < 3; ++c) {
            int off = w * 3072 + c * 1024;
            __builtin_amdgcn_global_load_lds(
                (const __attribute__((address_space(1))) void*)((const char*)kf + off + lane * 16),
                (__attribute__((address_space(3))) void*)((char*)&lds_k[0][0] + off),
                16, 0, 0);
        }
    } else {
        #pragma unroll
        for (int i = 0; i < 6; ++i) {
            int e = i * 512 + tid;
            int col = e / 24, dq = e - col * 24, d0 = dq * 4;
            float4 v; int f, dd;
            if (d0 < 64) {
                v = *reinterpret_cast<const float4*>(Kp + (size_t)bh * (SEQ * 64) + (size_t)col * 64 + d0);
                f = d0 >> 5; dd = d0 & 31;
            } else {
                v = *reinterpret_cast<const float4*>(PKp + (size_t)bh * (SEQ * 32) + (size_t)col * 32 + (d0 - 64));
                f = 2; dd = d0 - 64;
            }
            int ll = (col & 15) | ((dd >> 3) << 4);
            int st2 = col >> 4, j = dd & 7;
            short4v s4;
            s4[0] = f2bf(clip5(v.x)); s4[1] = f2bf(clip5(v.y));
            s4[2] = f2bf(clip5(v.z)); s4[3] = f2bf(clip5(v.w));
            *reinterpret_cast<short4v*>(&lds_k[0][(((st2 * 3 + f) * 64 + ll) << 3) + j]) = s4;
        }
    }
    __syncthreads();   // drains stage-0 (vmcnt/lgkmcnt) for all waves

    // ---- main loop: prefetch t+1, compute t, one barrier per tile ----
    #pragma unroll
    for (int t = 0; t < TILES; ++t) {
        if (t + 1 < TILES) {
            if constexpr (USEWS) {
                const char* ksrc = (const char*)kf + (size_t)(t + 1) * FRAG_BYTES;
                #pragma unroll
                for (int c = 0; c < 3; ++c) {
                    int off = w * 3072 + c * 1024;
                    __builtin_amdgcn_global_load_lds(
                        (const __attribute__((address_space(1))) void*)(ksrc + off + lane * 16),
                        (__attribute__((address_space(3))) void*)((char*)&lds_k[(t + 1) & 1][0] + off),
                        16, 0, 0);
                }
            } else {
                const int tile0 = (t + 1) * 128;
                #pragma unroll
                for (int i = 0; i < 6; ++i) {
                    int e = i * 512 + tid;
                    int col = e / 24, dq = e - col * 24, d0 = dq * 4;
                    int colg = tile0 + col;
                    float4 v; int f, dd;
                    if (d0 < 64) {
                        v = *reinterpret_cast<const float4*>(Kp + (size_t)bh * (SEQ * 64) + (size_t)colg * 64 + d0);
                        f = d0 >> 5; dd = d0 & 31;
                    } else {
                        v = *reinterpret_cast<const float4*>(PKp + (size_t)bh * (SEQ * 32) + (size_t)colg * 32 + (d0 - 64));
                        f = 2; dd = d0 - 64;
                    }
                    int ll = (col & 15) | ((dd >> 3) << 4);
                    int st2 = col >> 4, j = dd & 7;
                    short4v s4;
                    s4[0] = f2bf(clip5(v.x)); s4[1] = f2bf(clip5(v.y));
                    s4[2] = f2bf(clip5(v.z)); s4[3] = f2bf(clip5(v.w));
                    *reinterpret_cast<short4v*>(&lds_k[(t + 1) & 1][(((st2 * 3 + f) * 64 + ll) << 3) + j]) = s4;
                }
            }
        }
        const short* lk = &lds_k[t & 1][0];
        #pragma unroll
        for (int sti = 0; sti < 2; ++sti) {
            const int st = cs * 2 + sti;
            bf16x8 kb0 = *reinterpret_cast<const bf16x8*>(lk + ((st * 3 + 0) * 64 + lane) * 8);
            bf16x8 kb1 = *reinterpret_cast<const bf16x8*>(lk + ((st * 3 + 1) * 64 + lane) * 8);
            bf16x8 kb2 = *reinterpret_cast<const bf16x8*>(lk + ((st * 3 + 2) * 64 + lane) * 8);
            CSTEP(kb0, kb1, kb2, t, sti, st);
        }
        __syncthreads();  // drains prefetch (issued before compute) + protects buffer reuse
    }

    // ---- row-sum reduce: in-wave then cross-wave via LDS ----
    float s = ssum;
    s += __shfl_xor(s, 16);
    s += __shfl_xor(s, 32);
    if (lane < 16) sred[w][l15] = s;
    __syncthreads();
    const float rs = sred[rg][l15] + sred[2 + rg][l15] + sred[4 + rg][l15] + sred[6 + rg][l15];
    const float inv = 1.0f / rs;

    // ---- scale + store: float4 per lane ----
    #pragma unroll
    for (int t = 0; t < TILES; ++t) {
        #pragma unroll
        for (int sti = 0; sti < 2; ++sti) {
            unsigned u0 = pk[t * 4 + sti * 2];
            unsigned u1 = pk[t * 4 + sti * 2 + 1];
            f32x4 pv = { bflo2f(u0) * inv, bfhi2f(u0) * inv,
                         bflo2f(u1) * inv, bfhi2f(u1) * inv };
            *reinterpret_cast<f32x4*>(orow + t * 128 + (cs * 2 + sti) * 16 + l4 * 4) = pv;
        }
    }
}

extern "C" void kernel_launch(void* const* d_in, const int* in_sizes, int n_in,
                              void* d_out, int out_size, void* d_ws, size_t ws_size,
                              hipStream_t stream) {
    const float* keys      = (const float*)d_in[0];
    const float* queries   = (const float*)d_in[1];
    const float* pos_key   = (const float*)d_in[2];
    const float* pos_query = (const float*)d_in[3];
    const int*   mask      = (const int*)d_in[4];
    float* outp = (float*)d_out;

    const size_t need = (size_t)32 * TILES * FRAG_SHORTS * sizeof(short); // 12.58 MB
    if (ws_size >= need) {
        short* wsK = (short*)d_ws;
        prep_kernel<<<dim3(6144), dim3(256), 0, stream>>>(keys, pos_key, wsK);
        attn_map_kernel<true><<<dim3(2048), dim3(512), 0, stream>>>(
            keys, queries, pos_key, pos_query, mask, wsK, outp);
    } else {
        attn_map_kernel<false><<<dim3(2048), dim3(512), 0, stream>>>(
            keys, queries, pos_key, pos_query, mask, nullptr, outp);
    }
}